// Round 5
// baseline (210.940 us; speedup 1.0000x reference)
//
#include <hip/hip_runtime.h>
#include <hip/hip_bf16.h>

// Problem constants
constexpr int Bc = 32, Sc = 4096, Dc = 64, Pc = 8, STRIDEc = 4, Hc = 512;
constexpr int Tc = (Sc - Pc) / STRIDEc + 1;   // 1023
constexpr int Kc = Pc * Dc;                   // 512
constexpr float EPSc = 1e-6f;

typedef __bf16 bf16x8 __attribute__((ext_vector_type(8)));
typedef unsigned short ushort8 __attribute__((ext_vector_type(8)));
typedef float f32x4 __attribute__((ext_vector_type(4)));
typedef unsigned int uint4v __attribute__((ext_vector_type(4)));

__device__ __forceinline__ int n_tok_of(int len) {
    return (len >= Pc) ? ((len - Pc) / STRIDEc + 1) : 1;
}

// fp32 -> bf16 round-to-nearest-even
__device__ __forceinline__ unsigned short f2bf(float f) {
    unsigned u = __builtin_bit_cast(unsigned, f);
    u = (u + 0x7FFFu + ((u >> 16) & 1u)) >> 16;
    return (unsigned short)u;
}
// pack two fp32 -> one uint holding (bf16(lo) | bf16(hi)<<16)
__device__ __forceinline__ unsigned pk2bf(float lo, float hi) {
    return (unsigned)f2bf(lo) | ((unsigned)f2bf(hi) << 16);
}

// ---------------------------------------------------------------------------
// Prep: emit W as bf16 in MFMA A-fragment order:
//   chunk(step, w, ct) of 512 elems; lane = quad*16+l15 holds 8 k's:
//   elem(n = w*128+ct*16+l15, k = step*32+quad*8+j) at
//   Wfrag[ chunk*512 + lane*8 + j ],  chunk = (step*4+w)*8+ct.
// grid (16,16) tiles of 32x32 (k0 = bx*32, n0 = by*32), 256 threads.
// Also writes token_lengths.
// ---------------------------------------------------------------------------
__global__ __launch_bounds__(256) void prep_kernel(
        const float* __restrict__ W, const int* __restrict__ lengths,
        unsigned short* __restrict__ Wfrag, float* __restrict__ out_tl) {
    __shared__ float tile[32][33];
    const int k0 = blockIdx.x * 32, n0 = blockIdx.y * 32;
    const int r = threadIdx.x >> 3, c = (threadIdx.x & 7) * 4;
    const float4 v = *(const float4*)(W + (size_t)(k0 + r) * Hc + n0 + c);
    tile[c + 0][r] = v.x;
    tile[c + 1][r] = v.y;
    tile[c + 2][r] = v.z;
    tile[c + 3][r] = v.w;
    __syncthreads();
    ushort4 o;
    o.x = f2bf(tile[r][c + 0]);
    o.y = f2bf(tile[r][c + 1]);
    o.z = f2bf(tile[r][c + 2]);
    o.w = f2bf(tile[r][c + 3]);
    // this thread holds n = n0 + r, k = k0 + c .. c+3
    const int n   = n0 + r;
    const int kk  = k0 + c;
    const int wv  = n >> 7;
    const int ct  = (n >> 4) & 7;
    const int l15 = n & 15;
    const int stp = kk >> 5;
    const int qd  = (kk >> 3) & 3;
    const size_t off =
        ((((size_t)stp * 4 + wv) * 8 + ct) * 64 + qd * 16 + l15) * 8 + (kk & 7);
    *(ushort4*)(Wfrag + off) = o;
    if (blockIdx.x == 0 && blockIdx.y == 0 && threadIdx.x < Bc)
        out_tl[threadIdx.x] = (float)n_tok_of(lengths[threadIdx.x]);
}

// ---------------------------------------------------------------------------
// Fused: tokens-write + bf16-MFMA GEMM (BM=64 x BN=512) + bias + RMSNorm*scale.
// Barrier-free K-loop: B-fragments loaded directly from Wfrag (L2-hot,
// fragment-ordered); token-fragments loaded directly from x (contiguous 32B
// slices, L1-hot) and packed to bf16 in-register. No LDS in the GEMM loop.
// Operand-swapped MFMA (D^T): lane l15 = token row, quad*4+reg = 4 consecutive
// h-cols -> float4 stores, in-register RMS partial sums.
// ---------------------------------------------------------------------------
__global__ __launch_bounds__(256, 2) void fused_kernel(
        const float* __restrict__ x, const int* __restrict__ lengths,
        const unsigned short* __restrict__ Wfrag, const float* __restrict__ bias,
        const float* __restrict__ scale, float* __restrict__ hidden,
        float* __restrict__ tokens) {
    const int b  = blockIdx.y;
    const int t0 = blockIdx.x * 64;
    const int len = lengths[b];
    const int ntok = n_tok_of(len);

    __shared__ float ssbuf[4][64];

    const int tid  = threadIdx.x;
    const int w    = tid >> 6;
    const int lane = tid & 63;
    const int l15  = lane & 15;
    const int quad = lane >> 4;

    f32x4 acc[4][8];                             // [ttile][ctile]
#pragma unroll
    for (int tt = 0; tt < 4; ++tt)
#pragma unroll
        for (int ct = 0; ct < 8; ++ct) acc[tt][ct] = (f32x4){0.f, 0.f, 0.f, 0.f};

    const float* xb   = x + (size_t)b * (Sc * Dc);
    float*       tokb = tokens + (size_t)b * Tc * Kc;

    // tokens-write coordinates: 2 float4 chunks per thread per step
    int a_r[2], a_c[2];
#pragma unroll
    for (int it = 0; it < 2; ++it) {
        const int l = tid + it * 256;
        a_r[it] = l >> 3;                        // row in tile (0..63)
        a_c[it] = (l & 7) * 4;                   // k offset within 32-k slice
    }
    // fragment rows for this lane
    int ft[4];
#pragma unroll
    for (int tt = 0; tt < 4; ++tt) ft[tt] = t0 + tt * 16 + l15;

    const unsigned short* wf = Wfrag + ((size_t)w * 8) * 512 + (size_t)lane * 8;

    for (int step = 0; step < 16; ++step) {
        const int k0 = step * 32;

        // ---- tokens: masked x load + store (also warms L1 for frags) ----
#pragma unroll
        for (int it = 0; it < 2; ++it) {
            const int t = t0 + a_r[it];
            const int kk = k0 + a_c[it];
            const int pos = t * STRIDEc + (kk >> 6);
            float4 v = make_float4(0.f, 0.f, 0.f, 0.f);
            if (t < ntok && pos < len)
                v = *(const float4*)(xb + (size_t)t * (STRIDEc * Dc) + kk);
            if (t < Tc)
                *(float4*)(tokb + (size_t)t * Kc + kk) = v;
        }

        // ---- B fragments straight from Wfrag (L2) ----
        ushort8 aW[8];
        const unsigned short* wfs = wf + (size_t)step * (4 * 8 * 512);
#pragma unroll
        for (int ct = 0; ct < 8; ++ct)
            aW[ct] = *(const ushort8*)(wfs + ct * 512);

        // ---- token fragments straight from x, packed to bf16 ----
        bf16x8 btok[4];
        const int kf = k0 + quad * 8;
        const int pf = kf >> 6;                  // single patch idx per 8-group
#pragma unroll
        for (int tt = 0; tt < 4; ++tt) {
            const int t = ft[tt];
            float4 f0 = make_float4(0.f, 0.f, 0.f, 0.f);
            float4 f1 = make_float4(0.f, 0.f, 0.f, 0.f);
            if (t < ntok && (t * STRIDEc + pf) < len) {
                const float* src = xb + (size_t)t * (STRIDEc * Dc) + kf;
                f0 = *(const float4*)(src);
                f1 = *(const float4*)(src + 4);
            }
            uint4v uu;
            uu[0] = pk2bf(f0.x, f0.y);
            uu[1] = pk2bf(f0.z, f0.w);
            uu[2] = pk2bf(f1.x, f1.y);
            uu[3] = pk2bf(f1.z, f1.w);
            btok[tt] = __builtin_bit_cast(bf16x8, uu);
        }

        // ---- MFMA (operand-swapped) ----
#pragma unroll
        for (int ct = 0; ct < 8; ++ct) {
            const bf16x8 av = __builtin_bit_cast(bf16x8, aW[ct]);
#pragma unroll
            for (int tt = 0; tt < 4; ++tt)
                acc[tt][ct] = __builtin_amdgcn_mfma_f32_16x16x32_bf16(
                    av, btok[tt], acc[tt][ct], 0, 0, 0);
        }
    }

    // ---- epilogue: bias, in-register row sums, RMS, scale, float4 stores ----
    float ss[4] = {0.f, 0.f, 0.f, 0.f};
#pragma unroll
    for (int ct = 0; ct < 8; ++ct) {
        const f32x4 b4 = *(const f32x4*)(bias + w * 128 + ct * 16 + quad * 4);
#pragma unroll
        for (int tt = 0; tt < 4; ++tt) {
            f32x4 h = acc[tt][ct] + b4;
            acc[tt][ct] = h;
            ss[tt] += h[0] * h[0] + h[1] * h[1] + h[2] * h[2] + h[3] * h[3];
        }
    }
#pragma unroll
    for (int tt = 0; tt < 4; ++tt) {
        float s = ss[tt];
        s += __shfl_xor(s, 16);
        s += __shfl_xor(s, 32);
        if (quad == 0) ssbuf[w][tt * 16 + l15] = s;
    }
    __syncthreads();
    float rstd[4];
#pragma unroll
    for (int tt = 0; tt < 4; ++tt) {
        const int r = tt * 16 + l15;
        const float tot = ssbuf[0][r] + ssbuf[1][r] + ssbuf[2][r] + ssbuf[3][r];
        rstd[tt] = rsqrtf(tot * (1.0f / (float)Hc) + EPSc);
    }
#pragma unroll
    for (int ct = 0; ct < 8; ++ct) {
        const f32x4 s4 = *(const f32x4*)(scale + w * 128 + ct * 16 + quad * 4);
#pragma unroll
        for (int tt = 0; tt < 4; ++tt) {
            const int t = ft[tt];
            if (t < Tc) {
                f32x4 o = acc[tt][ct] * rstd[tt] * s4;
                *(f32x4*)(hidden + ((size_t)b * Tc + t) * Hc
                          + w * 128 + ct * 16 + quad * 4) = o;
            }
        }
    }
}

extern "C" void kernel_launch(void* const* d_in, const int* in_sizes, int n_in,
                              void* d_out, int out_size, void* d_ws, size_t ws_size,
                              hipStream_t stream) {
    const float* x       = (const float*)d_in[0];
    const int*   lengths = (const int*)d_in[1];
    const float* W       = (const float*)d_in[2];
    const float* bias    = (const float*)d_in[3];
    const float* scale   = (const float*)d_in[4];

    const size_t BTH = (size_t)Bc * Tc * Hc;   // 16,760,832
    float* out    = (float*)d_out;
    float* hidden = out;                        // output 0
    float* tl     = out + BTH;                  // output 1 (32 floats)
    float* tokens = out + BTH + Bc;             // output 2

    unsigned short* Wfrag = (unsigned short*)d_ws; // 512x512 bf16, fragment-ordered

    {   // W -> Wfrag (transpose + bf16 + fragment order) and token_lengths
        dim3 grid(Hc / 32, Hc / 32);            // (16,16)
        prep_kernel<<<grid, 256, 0, stream>>>(W, lengths, Wfrag, tl);
    }
    {   // fused tokens + GEMM + RMSNorm, barrier-free K-loop
        dim3 grid(16, Bc);                      // 16 m-blocks x 32 batches
        fused_kernel<<<grid, 256, 0, stream>>>(x, lengths, Wfrag, bias, scale,
                                               hidden, tokens);
    }
}